// Round 2
// baseline (5028.072 us; speedup 1.0000x reference)
//
#include <hip/hip_runtime.h>
#include <math.h>

// ---------------- device helpers ----------------

__device__ __forceinline__ float elu_f(float x) {
    return x > 0.f ? x : expm1f(x);
}

// float atomic max via int/uint monotone trick (init must be -inf)
__device__ __forceinline__ void atomicMaxF(float* addr, float val) {
    if (val >= 0.f)
        atomicMax((int*)addr, __float_as_int(val));
    else
        atomicMin((unsigned int*)addr, __float_as_uint(val));
}

// ---------------- kernels ----------------

// fused 2-layer MLP: out = elu(elu(x@A+ab)@B+bb), 23->23->23, one thread per node
__global__ void mlp_kernel(const float* __restrict__ x,
                           const float* __restrict__ A, const float* __restrict__ ab,
                           const float* __restrict__ B, const float* __restrict__ bb,
                           float* __restrict__ out, int n) {
    __shared__ float sA[23 * 23], sB[23 * 23], sa[23], sb[23];
    for (int t = threadIdx.x; t < 23 * 23; t += blockDim.x) { sA[t] = A[t]; sB[t] = B[t]; }
    if (threadIdx.x < 23) { sa[threadIdx.x] = ab[threadIdx.x]; sb[threadIdx.x] = bb[threadIdx.x]; }
    __syncthreads();
    int i = blockIdx.x * blockDim.x + threadIdx.x;
    if (i >= n) return;
    float xi[23], h1[23];
    #pragma unroll
    for (int j = 0; j < 23; j++) xi[j] = x[(size_t)i * 23 + j];
    #pragma unroll
    for (int o = 0; o < 23; o++) {
        float acc = sa[o];
        #pragma unroll
        for (int j = 0; j < 23; j++) acc = fmaf(xi[j], sA[j * 23 + o], acc);
        h1[o] = elu_f(acc);
    }
    #pragma unroll
    for (int o = 0; o < 23; o++) {
        float acc = sb[o];
        #pragma unroll
        for (int j = 0; j < 23; j++) acc = fmaf(h1[j], sB[j * 23 + o], acc);
        out[(size_t)i * 23 + o] = elu_f(acc);
    }
}

// out[node, oc] = b[oc] + sum_j in[node,j] * W[j,oc]
// blockDim.x = OUT (coalesced W reads), blockDim.y = nodes per block
__global__ void proj_kernel(const float* __restrict__ in, const float* __restrict__ W,
                            const float* __restrict__ b, float* __restrict__ out,
                            int n, int IN, int OUT) {
    int node = blockIdx.x * blockDim.y + threadIdx.y;
    int oc = threadIdx.x;
    if (node >= n) return;
    const float* xi = in + (size_t)node * IN;
    float acc = b[oc];
    for (int j = 0; j < IN; j++) acc = fmaf(xi[j], W[(size_t)j * OUT + oc], acc);
    out[(size_t)node * OUT + oc] = acc;
}

__global__ void init_softmax_kernel(float* __restrict__ mx, float* __restrict__ dn, int n) {
    int i = blockIdx.x * blockDim.x + threadIdx.x;
    if (i < n) { mx[i] = -INFINITY; dn[i] = 0.f; }
}

// RECOMPUTE variant: q,k projected on the fly from node features.
// thread per (edge, head); H=8 fixed.  logit = scale * sum_c q_c*(k_c+e_c)
template<int IN, int C>
__global__ void logits_rc_kernel(const float* __restrict__ feat,
                                 const float* __restrict__ Wq, const float* __restrict__ qb,
                                 const float* __restrict__ Wk, const float* __restrict__ kb,
                                 const float* __restrict__ ea, const float* __restrict__ We,
                                 const int* __restrict__ src, const int* __restrict__ dst,
                                 float* __restrict__ lg, float* __restrict__ mx,
                                 int nE, float scale) {
    const int HC = 8 * C;
    int idx = blockIdx.x * blockDim.x + threadIdx.x;
    if (idx >= nE * 8) return;
    int e = idx >> 3, h = idx & 7;
    int s = src[e], d = dst[e];
    const float* fd = feat + (size_t)d * IN;
    const float* fs = feat + (size_t)s * IN;
    float qa[C], ka[C];
    #pragma unroll
    for (int c = 0; c < C; c++) { qa[c] = qb[h * C + c]; ka[c] = kb[h * C + c]; }
    for (int j = 0; j < IN; j++) {
        float fdj = fd[j], fsj = fs[j];
        const float* wq = Wq + (size_t)j * HC + h * C;
        const float* wk = Wk + (size_t)j * HC + h * C;
        #pragma unroll
        for (int c = 0; c < C; c++) {
            qa[c] = fmaf(fdj, wq[c], qa[c]);
            ka[c] = fmaf(fsj, wk[c], ka[c]);
        }
    }
    const float* eav = ea + (size_t)e * 7;
    float ev[7];
    #pragma unroll
    for (int j = 0; j < 7; j++) ev[j] = eav[j];
    float acc = 0.f;
    #pragma unroll
    for (int c = 0; c < C; c++) {
        float ec = 0.f;
        #pragma unroll
        for (int j = 0; j < 7; j++) ec = fmaf(ev[j], We[(size_t)j * HC + h * C + c], ec);
        acc = fmaf(qa[c], ka[c] + ec, acc);
    }
    acc *= scale;
    lg[idx] = acc;
    atomicMaxF(&mx[(size_t)d * 8 + h], acc);
}

// MATERIALIZED variant (used for conv2 when workspace allows)
template<int C>
__global__ void logits_mat_kernel(const float* __restrict__ q, const float* __restrict__ k,
                                  const float* __restrict__ ea, const float* __restrict__ We,
                                  const int* __restrict__ src, const int* __restrict__ dst,
                                  float* __restrict__ lg, float* __restrict__ mx,
                                  int nE, float scale) {
    const int HC = 8 * C;
    int idx = blockIdx.x * blockDim.x + threadIdx.x;
    if (idx >= nE * 8) return;
    int e = idx >> 3, h = idx & 7;
    int s = src[e], d = dst[e];
    const float* eav = ea + (size_t)e * 7;
    float ev[7];
    #pragma unroll
    for (int j = 0; j < 7; j++) ev[j] = eav[j];
    const float* kp = k + (size_t)s * HC + h * C;
    const float* qp = q + (size_t)d * HC + h * C;
    const float* Wp = We + h * C;
    float acc = 0.f;
    #pragma unroll
    for (int c = 0; c < C; c++) {
        float ec = 0.f;
        #pragma unroll
        for (int j = 0; j < 7; j++) ec = fmaf(ev[j], Wp[j * HC + c], ec);
        acc = fmaf(qp[c], kp[c] + ec, acc);
    }
    acc *= scale;
    lg[idx] = acc;
    atomicMaxF(&mx[(size_t)d * 8 + h], acc);
}

// thread per (edge, head): ex = exp(l - m[dst]); lg <- ex; denom += ex
__global__ void expsum_kernel(const int* __restrict__ dst, float* __restrict__ lg,
                              const float* __restrict__ mx, float* __restrict__ dn, int nE) {
    int idx = blockIdx.x * blockDim.x + threadIdx.x;
    if (idx >= nE * 8) return;
    int e = idx >> 3, h = idx & 7;
    int d = dst[e];
    float ex = expf(lg[idx] - mx[(size_t)d * 8 + h]);
    lg[idx] = ex;
    atomicAdd(&dn[(size_t)d * 8 + h], ex);
}

// RECOMPUTE message: v projected on the fly.  blockDim.x = H*C, blockDim.y = edges/block
template<int IN, int C>
__global__ void message_rc_kernel(const float* __restrict__ feat,
                                  const float* __restrict__ Wv, const float* __restrict__ vb,
                                  const float* __restrict__ ea, const float* __restrict__ We,
                                  const int* __restrict__ src, const int* __restrict__ dst,
                                  const float* __restrict__ ex, const float* __restrict__ dn,
                                  float* __restrict__ agg, int nE) {
    const int HC = 8 * C;
    int e = blockIdx.x * blockDim.y + threadIdx.y;
    if (e >= nE) return;
    int ch = threadIdx.x;
    int h = ch / C;
    int s = src[e], d = dst[e];
    float alpha = ex[(size_t)e * 8 + h] / dn[(size_t)d * 8 + h];
    const float* fs = feat + (size_t)s * IN;
    float acc = vb[ch];
    for (int j = 0; j < IN; j++) acc = fmaf(fs[j], Wv[(size_t)j * HC + ch], acc);
    const float* eav = ea + (size_t)e * 7;
    #pragma unroll
    for (int j = 0; j < 7; j++) acc = fmaf(eav[j], We[(size_t)j * HC + ch], acc);
    atomicAdd(&agg[(size_t)d * HC + ch], alpha * acc);
}

// MATERIALIZED message (conv2 tier A)
template<int C>
__global__ void message_mat_kernel(const float* __restrict__ v, const float* __restrict__ ea,
                                   const float* __restrict__ We, const int* __restrict__ src,
                                   const int* __restrict__ dst, const float* __restrict__ ex,
                                   const float* __restrict__ dn, float* __restrict__ agg,
                                   int nE) {
    const int HC = 8 * C;
    int e = blockIdx.x * blockDim.y + threadIdx.y;
    if (e >= nE) return;
    int ch = threadIdx.x;
    int h = ch / C;
    int s = src[e], d = dst[e];
    float alpha = ex[(size_t)e * 8 + h] / dn[(size_t)d * 8 + h];
    const float* eav = ea + (size_t)e * 7;
    float acc = v[(size_t)s * HC + ch];
    #pragma unroll
    for (int j = 0; j < 7; j++) acc = fmaf(eav[j], We[(size_t)j * HC + ch], acc);
    atomicAdd(&agg[(size_t)d * HC + ch], alpha * acc);
}

__global__ void elu_kernel(float* __restrict__ a, size_t n) {
    size_t i = (size_t)blockIdx.x * blockDim.x + threadIdx.x;
    if (i < n) a[i] = elu_f(a[i]);
}

// head: out = elu(elu(h)@W1+b1)@W2 + b2 ; elu applied to h on load
__global__ void head_kernel(const float* __restrict__ h, const float* __restrict__ W1,
                            const float* __restrict__ b1, const float* __restrict__ W2,
                            const float* __restrict__ b2, float* __restrict__ out, int n) {
    __shared__ float sW1[64 * 20], sb1[20], sW2[20], sb2;
    for (int t = threadIdx.x; t < 64 * 20; t += blockDim.x) sW1[t] = W1[t];
    if (threadIdx.x < 20) { sb1[threadIdx.x] = b1[threadIdx.x]; sW2[threadIdx.x] = W2[threadIdx.x]; }
    if (threadIdx.x == 0) sb2 = b2[0];
    __syncthreads();
    int i = blockIdx.x * blockDim.x + threadIdx.x;
    if (i >= n) return;
    float hv[64];
    const float* hp = h + (size_t)i * 64;
    #pragma unroll
    for (int j = 0; j < 64; j++) hv[j] = elu_f(hp[j]);
    float acc2 = sb2;
    for (int o = 0; o < 20; o++) {
        float a = sb1[o];
        #pragma unroll
        for (int j = 0; j < 64; j++) a = fmaf(hv[j], sW1[j * 20 + o], a);
        acc2 = fmaf(elu_f(a), sW2[o], acc2);
    }
    out[i] = acc2;
}

__global__ void zero_out_kernel(float* __restrict__ out, int n) {
    int i = blockIdx.x * blockDim.x + threadIdx.x;
    if (i < n) out[i] = 0.f;
}

// ---------------- launcher ----------------

extern "C" void kernel_launch(void* const* d_in, const int* in_sizes, int n_in,
                              void* d_out, int out_size, void* d_ws, size_t ws_size,
                              hipStream_t stream) {
    const float* x   = (const float*)d_in[0];
    const int*   ei  = (const int*)d_in[1];
    const float* ea  = (const float*)d_in[2];
    const float* Aw  = (const float*)d_in[3];
    const float* Ab  = (const float*)d_in[4];
    const float* Bw  = (const float*)d_in[5];
    const float* Bb  = (const float*)d_in[6];
    const float* q1w = (const float*)d_in[7];  const float* q1b = (const float*)d_in[8];
    const float* k1w = (const float*)d_in[9];  const float* k1b = (const float*)d_in[10];
    const float* v1w = (const float*)d_in[11]; const float* v1b = (const float*)d_in[12];
    const float* e1w = (const float*)d_in[13];
    const float* s1w = (const float*)d_in[14]; const float* s1b = (const float*)d_in[15];
    const float* q2w = (const float*)d_in[16]; const float* q2b = (const float*)d_in[17];
    const float* k2w = (const float*)d_in[18]; const float* k2b = (const float*)d_in[19];
    const float* v2w = (const float*)d_in[20]; const float* v2b = (const float*)d_in[21];
    const float* e2w = (const float*)d_in[22];
    const float* s2w = (const float*)d_in[23]; const float* s2b = (const float*)d_in[24];
    const float* l1w = (const float*)d_in[25]; const float* l1b = (const float*)d_in[26];
    const float* l2w = (const float*)d_in[27]; const float* l2b = (const float*)d_in[28];

    const int n  = in_sizes[0] / 23;
    const int nE = in_sizes[1] / 2;
    const int* src = ei;
    const int* dst = ei + nE;
    float* out = (float*)d_out;
    const int B = 256;

    // ---- workspace layout (floats) ----
    size_t fl_h1 = (size_t)n * 23;
    size_t fl_o1 = (size_t)n * 192;
    size_t fl_lg = (size_t)nE * 8;
    size_t fl_mx = (size_t)n * 8;
    size_t fl_dn = (size_t)n * 8;
    size_t fl_o2 = (size_t)n * 64;
    size_t base_floats  = fl_h1 + fl_o1 + fl_lg + fl_mx + fl_dn + fl_o2;
    size_t tierA_floats = base_floats + (size_t)3 * n * 64;  // + q2,k2,v2

    if (ws_size < base_floats * sizeof(float)) {
        // diagnostic: workspace too small for any correct plan -> emit zeros
        zero_out_kernel<<<(out_size + B - 1) / B, B, 0, stream>>>(out, out_size);
        return;
    }
    const bool mat2 = (ws_size >= tierA_floats * sizeof(float));

    float* ws = (float*)d_ws;
    size_t off = 0;
    float* h1 = ws + off; off += fl_h1;
    float* o1 = ws + off; off += fl_o1;
    float* lg = ws + off; off += fl_lg;
    float* mx = ws + off; off += fl_mx;
    float* dn = ws + off; off += fl_dn;
    float* o2 = ws + off; off += fl_o2;
    float* q2 = nullptr; float* k2 = nullptr; float* v2 = nullptr;
    if (mat2) {
        q2 = ws + off; off += (size_t)n * 64;
        k2 = ws + off; off += (size_t)n * 64;
        v2 = ws + off; off += (size_t)n * 64;
    }

    const float sc1 = 1.0f / sqrtf(24.0f);
    const float sc2 = 1.0f / sqrtf(8.0f);

    // 1) node MLP  x -> h1
    mlp_kernel<<<(n + B - 1) / B, B, 0, stream>>>(x, Aw, Ab, Bw, Bb, h1, n);

    // 2) conv1: skip projection into agg buffer o1
    proj_kernel<<<n, dim3(192, 1), 0, stream>>>(h1, s1w, s1b, o1, n, 23, 192);

    // 3) conv1 segment softmax + aggregate (q/k/v recomputed from h1)
    init_softmax_kernel<<<(n * 8 + B - 1) / B, B, 0, stream>>>(mx, dn, n * 8);
    logits_rc_kernel<23, 24><<<(nE * 8 + B - 1) / B, B, 0, stream>>>(
        h1, q1w, q1b, k1w, k1b, ea, e1w, src, dst, lg, mx, nE, sc1);
    expsum_kernel<<<(nE * 8 + B - 1) / B, B, 0, stream>>>(dst, lg, mx, dn, nE);
    message_rc_kernel<23, 24><<<(nE + 1) / 2, dim3(192, 2), 0, stream>>>(
        h1, v1w, v1b, ea, e1w, src, dst, lg, dn, o1, nE);

    // 4) elu on conv1 output -> h2 (in place)
    elu_kernel<<<(int)(((size_t)n * 192 + B - 1) / B), B, 0, stream>>>(o1, (size_t)n * 192);

    // 5) conv2: skip projection into o2
    proj_kernel<<<(n + 3) / 4, dim3(64, 4), 0, stream>>>(o1, s2w, s2b, o2, n, 192, 64);

    // 6) conv2 segment softmax + aggregate
    init_softmax_kernel<<<(n * 8 + B - 1) / B, B, 0, stream>>>(mx, dn, n * 8);
    if (mat2) {
        proj_kernel<<<(n + 3) / 4, dim3(64, 4), 0, stream>>>(o1, q2w, q2b, q2, n, 192, 64);
        proj_kernel<<<(n + 3) / 4, dim3(64, 4), 0, stream>>>(o1, k2w, k2b, k2, n, 192, 64);
        proj_kernel<<<(n + 3) / 4, dim3(64, 4), 0, stream>>>(o1, v2w, v2b, v2, n, 192, 64);
        logits_mat_kernel<8><<<(nE * 8 + B - 1) / B, B, 0, stream>>>(
            q2, k2, ea, e2w, src, dst, lg, mx, nE, sc2);
        expsum_kernel<<<(nE * 8 + B - 1) / B, B, 0, stream>>>(dst, lg, mx, dn, nE);
        message_mat_kernel<8><<<(nE + 3) / 4, dim3(64, 4), 0, stream>>>(
            v2, ea, e2w, src, dst, lg, dn, o2, nE);
    } else {
        logits_rc_kernel<192, 8><<<(nE * 8 + B - 1) / B, B, 0, stream>>>(
            o1, q2w, q2b, k2w, k2b, ea, e2w, src, dst, lg, mx, nE, sc2);
        expsum_kernel<<<(nE * 8 + B - 1) / B, B, 0, stream>>>(dst, lg, mx, dn, nE);
        message_rc_kernel<192, 8><<<(nE + 3) / 4, dim3(64, 4), 0, stream>>>(
            o1, v2w, v2b, ea, e2w, src, dst, lg, dn, o2, nE);
    }

    // 7) head: elu -> lin1 -> elu -> lin2
    head_kernel<<<(n + B - 1) / B, B, 0, stream>>>(o2, l1w, l1b, l2w, l2b, out, n);
}

// Round 3
// 3576.566 us; speedup vs baseline: 1.4058x; 1.4058x over previous
//
#include <hip/hip_runtime.h>
#include <math.h>

// ---------------- device helpers ----------------

__device__ __forceinline__ float elu_f(float x) {
    return x > 0.f ? x : expm1f(x);
}

// ---------------- node MLP ----------------

__global__ void mlp_kernel(const float* __restrict__ x,
                           const float* __restrict__ A, const float* __restrict__ ab,
                           const float* __restrict__ B, const float* __restrict__ bb,
                           float* __restrict__ out, int n) {
    __shared__ float sA[23 * 23], sB[23 * 23], sa[23], sb[23];
    for (int t = threadIdx.x; t < 23 * 23; t += blockDim.x) { sA[t] = A[t]; sB[t] = B[t]; }
    if (threadIdx.x < 23) { sa[threadIdx.x] = ab[threadIdx.x]; sb[threadIdx.x] = bb[threadIdx.x]; }
    __syncthreads();
    int i = blockIdx.x * blockDim.x + threadIdx.x;
    if (i >= n) return;
    float xi[23], h1[23];
    #pragma unroll
    for (int j = 0; j < 23; j++) xi[j] = x[(size_t)i * 23 + j];
    #pragma unroll
    for (int o = 0; o < 23; o++) {
        float acc = sa[o];
        #pragma unroll
        for (int j = 0; j < 23; j++) acc = fmaf(xi[j], sA[j * 23 + o], acc);
        h1[o] = elu_f(acc);
    }
    #pragma unroll
    for (int o = 0; o < 23; o++) {
        float acc = sb[o];
        #pragma unroll
        for (int j = 0; j < 23; j++) acc = fmaf(h1[j], sB[j * 23 + o], acc);
        out[(size_t)i * 23 + o] = elu_f(acc);
    }
}

// ---------------- dense projection ----------------
// out[node, oc] = b[oc] + sum_j in[node,j] * W[j,oc]
__global__ void proj_kernel(const float* __restrict__ in, const float* __restrict__ W,
                            const float* __restrict__ b, float* __restrict__ out,
                            int n, int IN, int OUT) {
    int node = blockIdx.x * blockDim.y + threadIdx.y;
    int oc = threadIdx.x;
    if (node >= n) return;
    const float* xi = in + (size_t)node * IN;
    float acc = b[oc];
    for (int j = 0; j < IN; j++) acc = fmaf(xi[j], W[(size_t)j * OUT + oc], acc);
    out[(size_t)node * OUT + oc] = acc;
}

// ---------------- CSR build ----------------

__global__ void zero2_kernel(int* __restrict__ a, int* __restrict__ b, int n) {
    int i = blockIdx.x * blockDim.x + threadIdx.x;
    if (i < n) { a[i] = 0; b[i] = 0; }
}

__global__ void count_kernel(const int* __restrict__ dst, int* __restrict__ cnt, int nE) {
    int e = blockIdx.x * blockDim.x + threadIdx.x;
    if (e < nE) atomicAdd(&cnt[dst[e]], 1);
}

// in-place per-256-block exclusive scan; bsum[b] = block total
__global__ void scan_block_kernel(int* __restrict__ cnt, int* __restrict__ bsum, int n) {
    __shared__ int sdat[256];
    int i = blockIdx.x * 256 + threadIdx.x;
    int v = (i < n) ? cnt[i] : 0;
    sdat[threadIdx.x] = v;
    __syncthreads();
    for (int off = 1; off < 256; off <<= 1) {
        int t = (threadIdx.x >= (unsigned)off) ? sdat[threadIdx.x - off] : 0;
        __syncthreads();
        sdat[threadIdx.x] += t;
        __syncthreads();
    }
    if (i < n) cnt[i] = sdat[threadIdx.x] - v;   // exclusive within block
    if (threadIdx.x == 255) bsum[blockIdx.x] = sdat[255];
}

// single-block exclusive scan of bsum (nb <= 1024)
__global__ void scan_bsum_kernel(int* __restrict__ bsum, int nb) {
    __shared__ int s[1024];
    int i = threadIdx.x;
    int v = (i < nb) ? bsum[i] : 0;
    s[i] = v;
    __syncthreads();
    for (int off = 1; off < 1024; off <<= 1) {
        int t = (i >= off) ? s[i - off] : 0;
        __syncthreads();
        s[i] += t;
        __syncthreads();
    }
    if (i < nb) bsum[i] = s[i] - v;   // exclusive
}

__global__ void finalize_rp_kernel(const int* __restrict__ cnt, const int* __restrict__ bsum,
                                   int* __restrict__ rp, int n, int nE) {
    int i = blockIdx.x * blockDim.x + threadIdx.x;
    if (i < n) rp[i] = cnt[i] + bsum[i >> 8];
    if (i == n) rp[n] = nE;
}

__global__ void scatter_kernel(const int* __restrict__ src, const int* __restrict__ dst,
                               const int* __restrict__ rp, int* __restrict__ cur,
                               int* __restrict__ srcS, int* __restrict__ eidS, int nE) {
    int e = blockIdx.x * blockDim.x + threadIdx.x;
    if (e >= nE) return;
    int d = dst[e];
    int pos = rp[d] + atomicAdd(&cur[d], 1);
    srcS[pos] = src[e];
    eidS[pos] = e;
}

// ---------------- fused TransformerConv (one wave per dst node) ----------------
// lanes own CPL = HC/64 contiguous channels; head = lane/8 (8 lanes per head).
// online softmax over in-edges; q & skip projected per-dst in-wave; no atomics.
template<int IN, int C, bool VMAT, bool DOELU>
__global__ void conv_fused_kernel(const float* __restrict__ feat,
                                  const float* __restrict__ Wq, const float* __restrict__ qb,
                                  const float* __restrict__ Ws, const float* __restrict__ sb,
                                  const float* __restrict__ Wv, const float* __restrict__ vb,
                                  const float* __restrict__ kmat, const float* __restrict__ vmat,
                                  const float* __restrict__ ea, const float* __restrict__ We,
                                  const int* __restrict__ rp, const int* __restrict__ srcS,
                                  const int* __restrict__ eidS,
                                  float* __restrict__ out, int n, float scale) {
    constexpr int HC = 8 * C;
    constexpr int CPL = HC / 64;
    __shared__ float sWv[VMAT ? 4 : IN * HC];
    if constexpr (!VMAT) {
        for (int t = threadIdx.x; t < IN * HC; t += blockDim.x) sWv[t] = Wv[t];
        __syncthreads();
    }
    int lane = threadIdx.x & 63;
    int d = blockIdx.x * (blockDim.x >> 6) + (threadIdx.x >> 6);
    if (d >= n) return;
    const int ch0 = lane * CPL;

    // edge-projection weights held in registers
    float we[7][CPL];
    #pragma unroll
    for (int j = 0; j < 7; j++)
        #pragma unroll
        for (int c = 0; c < CPL; c++) we[j][c] = We[j * HC + ch0 + c];

    float vbr[CPL];
    if constexpr (!VMAT) {
        #pragma unroll
        for (int c = 0; c < CPL; c++) vbr[c] = vb[ch0 + c];
    }

    // q and skip projections for this dst
    float q[CPL], sk[CPL];
    #pragma unroll
    for (int c = 0; c < CPL; c++) { q[c] = qb[ch0 + c]; sk[c] = sb[ch0 + c]; }
    const float* fd = feat + (size_t)d * IN;
    for (int j = 0; j < IN; j++) {
        float f = fd[j];
        #pragma unroll
        for (int c = 0; c < CPL; c++) {
            q[c]  = fmaf(f, Wq[(size_t)j * HC + ch0 + c], q[c]);
            sk[c] = fmaf(f, Ws[(size_t)j * HC + ch0 + c], sk[c]);
        }
    }

    float m = -INFINITY, l = 0.f, acc[CPL];
    #pragma unroll
    for (int c = 0; c < CPL; c++) acc[c] = 0.f;

    int p0 = rp[d], p1 = rp[d + 1];
    for (int p = p0; p < p1; p++) {
        int s = srcS[p];
        int eid = eidS[p];
        const float* eav = ea + (size_t)eid * 7;
        float ev[7];
        #pragma unroll
        for (int j = 0; j < 7; j++) ev[j] = eav[j];

        const float* kp = kmat + (size_t)s * HC + ch0;
        float vv[CPL];
        float part = 0.f;
        #pragma unroll
        for (int c = 0; c < CPL; c++) {
            float ec = 0.f;
            #pragma unroll
            for (int j = 0; j < 7; j++) ec = fmaf(ev[j], we[j][c], ec);
            part = fmaf(q[c], kp[c] + ec, part);
            vv[c] = ec;
        }
        if constexpr (VMAT) {
            const float* vp = vmat + (size_t)s * HC + ch0;
            #pragma unroll
            for (int c = 0; c < CPL; c++) vv[c] += vp[c];
        } else {
            #pragma unroll
            for (int c = 0; c < CPL; c++) vv[c] += vbr[c];
            const float* fs = feat + (size_t)s * IN;
            for (int j = 0; j < IN; j++) {
                float f = fs[j];
                #pragma unroll
                for (int c = 0; c < CPL; c++) vv[c] = fmaf(f, sWv[j * HC + ch0 + c], vv[c]);
            }
        }
        // per-head logit: reduce over the 8 lanes of this head
        part += __shfl_xor(part, 1);
        part += __shfl_xor(part, 2);
        part += __shfl_xor(part, 4);
        float z = part * scale;
        // online softmax update
        float mn = fmaxf(m, z);
        float rs = expf(m - mn);      // m=-inf on first edge -> 0
        float pw = expf(z - mn);
        l = l * rs + pw;
        #pragma unroll
        for (int c = 0; c < CPL; c++) acc[c] = fmaf(acc[c], rs, pw * vv[c]);
        m = mn;
    }
    float invl = (l > 0.f) ? 1.f / l : 0.f;
    float* op = out + (size_t)d * HC + ch0;
    #pragma unroll
    for (int c = 0; c < CPL; c++) {
        float r = sk[c] + acc[c] * invl;
        op[c] = DOELU ? elu_f(r) : r;
    }
}

// ---------------- head ----------------
__global__ void head_kernel(const float* __restrict__ h, const float* __restrict__ W1,
                            const float* __restrict__ b1, const float* __restrict__ W2,
                            const float* __restrict__ b2, float* __restrict__ out, int n) {
    __shared__ float sW1[64 * 20], sb1[20], sW2[20], sb2;
    for (int t = threadIdx.x; t < 64 * 20; t += blockDim.x) sW1[t] = W1[t];
    if (threadIdx.x < 20) { sb1[threadIdx.x] = b1[threadIdx.x]; sW2[threadIdx.x] = W2[threadIdx.x]; }
    if (threadIdx.x == 0) sb2 = b2[0];
    __syncthreads();
    int i = blockIdx.x * blockDim.x + threadIdx.x;
    if (i >= n) return;
    float hv[64];
    const float* hp = h + (size_t)i * 64;
    #pragma unroll
    for (int j = 0; j < 64; j++) hv[j] = elu_f(hp[j]);
    float acc2 = sb2;
    for (int o = 0; o < 20; o++) {
        float a = sb1[o];
        #pragma unroll
        for (int j = 0; j < 64; j++) a = fmaf(hv[j], sW1[j * 20 + o], a);
        acc2 = fmaf(elu_f(a), sW2[o], acc2);
    }
    out[i] = acc2;
}

__global__ void zero_out_kernel(float* __restrict__ out, int n) {
    int i = blockIdx.x * blockDim.x + threadIdx.x;
    if (i < n) out[i] = 0.f;
}

// ---------------- launcher ----------------

extern "C" void kernel_launch(void* const* d_in, const int* in_sizes, int n_in,
                              void* d_out, int out_size, void* d_ws, size_t ws_size,
                              hipStream_t stream) {
    const float* x   = (const float*)d_in[0];
    const int*   ei  = (const int*)d_in[1];
    const float* ea  = (const float*)d_in[2];
    const float* Aw  = (const float*)d_in[3];
    const float* Ab  = (const float*)d_in[4];
    const float* Bw  = (const float*)d_in[5];
    const float* Bb  = (const float*)d_in[6];
    const float* q1w = (const float*)d_in[7];  const float* q1b = (const float*)d_in[8];
    const float* k1w = (const float*)d_in[9];  const float* k1b = (const float*)d_in[10];
    const float* v1w = (const float*)d_in[11]; const float* v1b = (const float*)d_in[12];
    const float* e1w = (const float*)d_in[13];
    const float* s1w = (const float*)d_in[14]; const float* s1b = (const float*)d_in[15];
    const float* q2w = (const float*)d_in[16]; const float* q2b = (const float*)d_in[17];
    const float* k2w = (const float*)d_in[18]; const float* k2b = (const float*)d_in[19];
    const float* v2w = (const float*)d_in[20]; const float* v2b = (const float*)d_in[21];
    const float* e2w = (const float*)d_in[22];
    const float* s2w = (const float*)d_in[23]; const float* s2b = (const float*)d_in[24];
    const float* l1w = (const float*)d_in[25]; const float* l1b = (const float*)d_in[26];
    const float* l2w = (const float*)d_in[27]; const float* l2b = (const float*)d_in[28];

    const int n  = in_sizes[0] / 23;
    const int nE = in_sizes[1] / 2;
    const int* src = ei;
    const int* dst = ei + nE;
    float* out = (float*)d_out;
    const int B = 256;
    const int nb = (n + 255) / 256;   // scan blocks (must be <= 1024)

    // ---- workspace layout ----
    size_t fl_h1 = (size_t)n * 23;
    size_t fl_o1 = (size_t)n * 192;
    size_t fl_o2 = (size_t)n * 64;
    size_t fl_k  = (size_t)n * 192;
    size_t fl_v  = (size_t)n * 192;
    size_t int_rp   = (size_t)n + 1;
    size_t int_cnt  = (size_t)n;
    size_t int_cur  = (size_t)n;
    size_t int_bs   = 1024;
    size_t int_srcS = (size_t)nE;
    size_t int_eidS = (size_t)nE;
    size_t ints_total = int_rp + int_cnt + int_cur + int_bs + int_srcS + int_eidS;

    size_t tier2_bytes = (fl_h1 + fl_o1 + fl_o2 + fl_k) * 4 + ints_total * 4;
    size_t tier1_bytes = tier2_bytes + fl_v * 4;

    if (ws_size < tier2_bytes || nb > 1024) {
        zero_out_kernel<<<(out_size + B - 1) / B, B, 0, stream>>>(out, out_size);
        return;
    }
    const bool vmat1 = (ws_size >= tier1_bytes);

    float* ws = (float*)d_ws;
    size_t off = 0;
    float* h1   = ws + off; off += fl_h1;
    float* o1   = ws + off; off += fl_o1;
    float* o2   = ws + off; off += fl_o2;
    float* kbuf = ws + off; off += fl_k;
    float* vbuf = nullptr;
    if (vmat1) { vbuf = ws + off; off += fl_v; }
    int* ip = (int*)(ws + off);
    int* rp   = ip;            ip += int_rp;
    int* cnt  = ip;            ip += int_cnt;
    int* cur  = ip;            ip += int_cur;
    int* bsum = ip;            ip += int_bs;
    int* srcS = ip;            ip += int_srcS;
    int* eidS = ip;            ip += int_eidS;

    // conv2 k/v alias conv1's k buffer (conv1 edge phase completes first)
    float* k2 = kbuf;
    float* v2 = kbuf + (size_t)n * 64;

    const float sc1 = 1.0f / sqrtf(24.0f);
    const float sc2 = 1.0f / sqrtf(8.0f);

    // ---- CSR build (independent of features) ----
    zero2_kernel<<<(n + B - 1) / B, B, 0, stream>>>(cnt, cur, n);
    count_kernel<<<(nE + B - 1) / B, B, 0, stream>>>(dst, cnt, nE);
    scan_block_kernel<<<nb, 256, 0, stream>>>(cnt, bsum, n);
    scan_bsum_kernel<<<1, 1024, 0, stream>>>(bsum, nb);
    finalize_rp_kernel<<<(n + 1 + B - 1) / B, B, 0, stream>>>(cnt, bsum, rp, n, nE);
    scatter_kernel<<<(nE + B - 1) / B, B, 0, stream>>>(src, dst, rp, cur, srcS, eidS, nE);

    // ---- node MLP ----
    mlp_kernel<<<(n + B - 1) / B, B, 0, stream>>>(x, Aw, Ab, Bw, Bb, h1, n);

    // ---- conv1: materialize k (and v if space), then fused edge phase ----
    proj_kernel<<<(n + 1) / 2, dim3(192, 2), 0, stream>>>(h1, k1w, k1b, kbuf, n, 23, 192);
    if (vmat1) {
        proj_kernel<<<(n + 1) / 2, dim3(192, 2), 0, stream>>>(h1, v1w, v1b, vbuf, n, 23, 192);
        conv_fused_kernel<23, 24, true, true><<<(n + 3) / 4, 256, 0, stream>>>(
            h1, q1w, q1b, s1w, s1b, v1w, v1b, kbuf, vbuf, ea, e1w,
            rp, srcS, eidS, o1, n, sc1);
    } else {
        conv_fused_kernel<23, 24, false, true><<<(n + 3) / 4, 256, 0, stream>>>(
            h1, q1w, q1b, s1w, s1b, v1w, v1b, kbuf, nullptr, ea, e1w,
            rp, srcS, eidS, o1, n, sc1);
    }

    // ---- conv2 ----
    proj_kernel<<<(n + 3) / 4, dim3(64, 4), 0, stream>>>(o1, k2w, k2b, k2, n, 192, 64);
    proj_kernel<<<(n + 3) / 4, dim3(64, 4), 0, stream>>>(o1, v2w, v2b, v2, n, 192, 64);
    conv_fused_kernel<192, 8, true, false><<<(n + 3) / 4, 256, 0, stream>>>(
        o1, q2w, q2b, s2w, s2b, v2w, v2b, k2, v2, ea, e2w,
        rp, srcS, eidS, o2, n, sc2);

    // ---- head ----
    head_kernel<<<(n + B - 1) / B, B, 0, stream>>>(o2, l1w, l1b, l2w, l2b, out, n);
}

// Round 4
// 1518.946 us; speedup vs baseline: 3.3102x; 2.3546x over previous
//
#include <hip/hip_runtime.h>
#include <math.h>

// ---------------- device helpers ----------------

__device__ __forceinline__ float elu_f(float x) {
    return x > 0.f ? x : expm1f(x);
}

// ---------------- node MLP ----------------

__global__ void mlp_kernel(const float* __restrict__ x,
                           const float* __restrict__ A, const float* __restrict__ ab,
                           const float* __restrict__ B, const float* __restrict__ bb,
                           float* __restrict__ out, int n) {
    __shared__ float sA[23 * 23], sB[23 * 23], sa[23], sb[23];
    for (int t = threadIdx.x; t < 23 * 23; t += blockDim.x) { sA[t] = A[t]; sB[t] = B[t]; }
    if (threadIdx.x < 23) { sa[threadIdx.x] = ab[threadIdx.x]; sb[threadIdx.x] = bb[threadIdx.x]; }
    __syncthreads();
    int i = blockIdx.x * blockDim.x + threadIdx.x;
    if (i >= n) return;
    float xi[23], h1[23];
    #pragma unroll
    for (int j = 0; j < 23; j++) xi[j] = x[(size_t)i * 23 + j];
    #pragma unroll
    for (int o = 0; o < 23; o++) {
        float acc = sa[o];
        #pragma unroll
        for (int j = 0; j < 23; j++) acc = fmaf(xi[j], sA[j * 23 + o], acc);
        h1[o] = elu_f(acc);
    }
    #pragma unroll
    for (int o = 0; o < 23; o++) {
        float acc = sb[o];
        #pragma unroll
        for (int j = 0; j < 23; j++) acc = fmaf(h1[j], sB[j * 23 + o], acc);
        out[(size_t)i * 23 + o] = elu_f(acc);
    }
}

// ---------------- fused multi-output projection ----------------
// Computes up to M projections of the same input in one pass.
// blockDim = (OUT, NPB). Input rows staged in LDS.
template<int IN, int OUT, int M, int NPB>
__global__ void proj_multi_kernel(const float* __restrict__ in,
    const float* __restrict__ W0, const float* __restrict__ b0, float* __restrict__ o0,
    const float* __restrict__ W1, const float* __restrict__ b1, float* __restrict__ o1,
    const float* __restrict__ W2, const float* __restrict__ b2, float* __restrict__ o2,
    const float* __restrict__ W3, const float* __restrict__ b3, float* __restrict__ o3,
    int n) {
    __shared__ float sIn[NPB][IN];
    const int node0 = blockIdx.x * NPB;
    const int tid = threadIdx.y * OUT + threadIdx.x;
    const int nth = OUT * NPB;
    for (int t = tid; t < NPB * IN; t += nth) {
        int nn = t / IN, jj = t - nn * IN;
        int g = node0 + nn;
        sIn[nn][jj] = (g < n) ? in[(size_t)g * IN + jj] : 0.f;
    }
    __syncthreads();
    const int node = node0 + threadIdx.y;
    if (node >= n) return;
    const int oc = threadIdx.x;
    const float* srow = sIn[threadIdx.y];
    float a0 = b0[oc], a1 = 0.f, a2 = 0.f, a3 = 0.f;
    if constexpr (M > 1) a1 = b1[oc];
    if constexpr (M > 2) a2 = b2[oc];
    if constexpr (M > 3) a3 = b3[oc];
    #pragma unroll 8
    for (int j = 0; j < IN; j++) {
        float f = srow[j];
        a0 = fmaf(f, W0[(size_t)j * OUT + oc], a0);
        if constexpr (M > 1) a1 = fmaf(f, W1[(size_t)j * OUT + oc], a1);
        if constexpr (M > 2) a2 = fmaf(f, W2[(size_t)j * OUT + oc], a2);
        if constexpr (M > 3) a3 = fmaf(f, W3[(size_t)j * OUT + oc], a3);
    }
    size_t idx = (size_t)node * OUT + oc;
    o0[idx] = a0;
    if constexpr (M > 1) o1[idx] = a1;
    if constexpr (M > 2) o2[idx] = a2;
    if constexpr (M > 3) o3[idx] = a3;
}

// ---------------- CSR build ----------------

__global__ void zero2_kernel(int* __restrict__ a, int* __restrict__ b, int n) {
    int i = blockIdx.x * blockDim.x + threadIdx.x;
    if (i < n) { a[i] = 0; b[i] = 0; }
}

__global__ void count_kernel(const int* __restrict__ dst, int* __restrict__ cnt, int nE) {
    int e = blockIdx.x * blockDim.x + threadIdx.x;
    if (e < nE) atomicAdd(&cnt[dst[e]], 1);
}

__global__ void scan_block_kernel(int* __restrict__ cnt, int* __restrict__ bsum, int n) {
    __shared__ int sdat[256];
    int i = blockIdx.x * 256 + threadIdx.x;
    int v = (i < n) ? cnt[i] : 0;
    sdat[threadIdx.x] = v;
    __syncthreads();
    for (int off = 1; off < 256; off <<= 1) {
        int t = (threadIdx.x >= (unsigned)off) ? sdat[threadIdx.x - off] : 0;
        __syncthreads();
        sdat[threadIdx.x] += t;
        __syncthreads();
    }
    if (i < n) cnt[i] = sdat[threadIdx.x] - v;
    if (threadIdx.x == 255) bsum[blockIdx.x] = sdat[255];
}

__global__ void scan_bsum_kernel(int* __restrict__ bsum, int nb) {
    __shared__ int s[1024];
    int i = threadIdx.x;
    int v = (i < nb) ? bsum[i] : 0;
    s[i] = v;
    __syncthreads();
    for (int off = 1; off < 1024; off <<= 1) {
        int t = (i >= off) ? s[i - off] : 0;
        __syncthreads();
        s[i] += t;
        __syncthreads();
    }
    if (i < nb) bsum[i] = s[i] - v;
}

__global__ void finalize_rp_kernel(const int* __restrict__ cnt, const int* __restrict__ bsum,
                                   int* __restrict__ rp, int n, int nE) {
    int i = blockIdx.x * blockDim.x + threadIdx.x;
    if (i < n) rp[i] = cnt[i] + bsum[i >> 8];
    if (i == n) rp[n] = nE;
}

__global__ void scatter_kernel(const int* __restrict__ src, const int* __restrict__ dst,
                               const int* __restrict__ rp, int* __restrict__ cur,
                               int* __restrict__ srcS, int* __restrict__ eidS, int nE) {
    int e = blockIdx.x * blockDim.x + threadIdx.x;
    if (e >= nE) return;
    int d = dst[e];
    int pos = rp[d] + atomicAdd(&cur[d], 1);
    srcS[pos] = src[e];
    eidS[pos] = e;
}

// ---------------- fused TransformerConv (one wave per dst node) ----------------
// lanes own CPL = HC/64 contiguous channels; head = lane/8.
// skip is pre-stored in out[]; q materialized (QMAT) or recomputed from feat.
// v materialized (VMAT) or recomputed from feat with Wv staged in LDS.
template<int IN, int C, bool VMAT, bool QMAT, bool DOELU>
__global__ void conv_fused_kernel(const float* __restrict__ feat,
                                  const float* __restrict__ Wq, const float* __restrict__ qb,
                                  const float* __restrict__ Wv, const float* __restrict__ vb,
                                  const float* __restrict__ kmat, const float* __restrict__ vmat,
                                  const float* __restrict__ qmat,
                                  const float* __restrict__ ea, const float* __restrict__ We,
                                  const int* __restrict__ rp, const int* __restrict__ srcS,
                                  const int* __restrict__ eidS,
                                  float* __restrict__ out, int n, float scale) {
    constexpr int HC = 8 * C;
    constexpr int CPL = HC / 64;
    __shared__ float sWv[VMAT ? 1 : IN * HC];
    if constexpr (!VMAT) {
        for (int t = threadIdx.x; t < IN * HC; t += blockDim.x) sWv[t] = Wv[t];
        __syncthreads();
    }
    const int lane = threadIdx.x & 63;
    const int d = blockIdx.x * (blockDim.x >> 6) + (threadIdx.x >> 6);
    if (d >= n) return;
    const int ch0 = lane * CPL;

    float we[7][CPL];
    #pragma unroll
    for (int j = 0; j < 7; j++)
        #pragma unroll
        for (int c = 0; c < CPL; c++) we[j][c] = We[j * HC + ch0 + c];

    float vbr[CPL];
    if constexpr (!VMAT) {
        #pragma unroll
        for (int c = 0; c < CPL; c++) vbr[c] = vb[ch0 + c];
    }

    float* op = out + (size_t)d * HC + ch0;
    float sk[CPL], q[CPL];
    #pragma unroll
    for (int c = 0; c < CPL; c++) sk[c] = op[c];   // pre-stored skip projection
    if constexpr (QMAT) {
        const float* qp = qmat + (size_t)d * HC + ch0;
        #pragma unroll
        for (int c = 0; c < CPL; c++) q[c] = qp[c];
    } else {
        #pragma unroll
        for (int c = 0; c < CPL; c++) q[c] = qb[ch0 + c];
        const float* fd = feat + (size_t)d * IN;
        for (int j = 0; j < IN; j++) {
            float f = fd[j];
            #pragma unroll
            for (int c = 0; c < CPL; c++)
                q[c] = fmaf(f, Wq[(size_t)j * HC + ch0 + c], q[c]);
        }
    }

    float m = -INFINITY, l = 0.f, acc[CPL];
    #pragma unroll
    for (int c = 0; c < CPL; c++) acc[c] = 0.f;

    const int p0 = rp[d], p1 = rp[d + 1];
    for (int p = p0; p < p1; p++) {
        int s = srcS[p];
        int eid = eidS[p];
        const float* eav = ea + (size_t)eid * 7;
        float ev[7];
        #pragma unroll
        for (int j = 0; j < 7; j++) ev[j] = eav[j];

        const float* kp = kmat + (size_t)s * HC + ch0;
        float vv[CPL];
        float part = 0.f;
        #pragma unroll
        for (int c = 0; c < CPL; c++) {
            float ec = 0.f;
            #pragma unroll
            for (int j = 0; j < 7; j++) ec = fmaf(ev[j], we[j][c], ec);
            part = fmaf(q[c], kp[c] + ec, part);
            vv[c] = ec;
        }
        if constexpr (VMAT) {
            const float* vp = vmat + (size_t)s * HC + ch0;
            #pragma unroll
            for (int c = 0; c < CPL; c++) vv[c] += vp[c];
        } else {
            #pragma unroll
            for (int c = 0; c < CPL; c++) vv[c] += vbr[c];
            const float* fs = feat + (size_t)s * IN;
            for (int j = 0; j < IN; j++) {
                float f = fs[j];
                #pragma unroll
                for (int c = 0; c < CPL; c++) vv[c] = fmaf(f, sWv[j * HC + ch0 + c], vv[c]);
            }
        }
        part += __shfl_xor(part, 1);
        part += __shfl_xor(part, 2);
        part += __shfl_xor(part, 4);
        float z = part * scale;
        float mn = fmaxf(m, z);
        float rs = expf(m - mn);
        float pw = expf(z - mn);
        l = l * rs + pw;
        #pragma unroll
        for (int c = 0; c < CPL; c++) acc[c] = fmaf(acc[c], rs, pw * vv[c]);
        m = mn;
    }
    float invl = (l > 0.f) ? 1.f / l : 0.f;
    #pragma unroll
    for (int c = 0; c < CPL; c++) {
        float r = sk[c] + acc[c] * invl;
        op[c] = DOELU ? elu_f(r) : r;
    }
}

// ---------------- head ----------------
__global__ void head_kernel(const float* __restrict__ h, const float* __restrict__ W1,
                            const float* __restrict__ b1, const float* __restrict__ W2,
                            const float* __restrict__ b2, float* __restrict__ out, int n) {
    __shared__ float sW1[64 * 20], sb1[20], sW2[20], sb2;
    for (int t = threadIdx.x; t < 64 * 20; t += blockDim.x) sW1[t] = W1[t];
    if (threadIdx.x < 20) { sb1[threadIdx.x] = b1[threadIdx.x]; sW2[threadIdx.x] = W2[threadIdx.x]; }
    if (threadIdx.x == 0) sb2 = b2[0];
    __syncthreads();
    int i = blockIdx.x * blockDim.x + threadIdx.x;
    if (i >= n) return;
    float hv[64];
    const float* hp = h + (size_t)i * 64;
    #pragma unroll
    for (int j = 0; j < 64; j++) hv[j] = elu_f(hp[j]);
    float acc2 = sb2;
    for (int o = 0; o < 20; o++) {
        float a = sb1[o];
        #pragma unroll
        for (int j = 0; j < 64; j++) a = fmaf(hv[j], sW1[j * 20 + o], a);
        acc2 = fmaf(elu_f(a), sW2[o], acc2);
    }
    out[i] = acc2;
}

__global__ void zero_out_kernel(float* __restrict__ out, int n) {
    int i = blockIdx.x * blockDim.x + threadIdx.x;
    if (i < n) out[i] = 0.f;
}

// ---------------- launcher ----------------

extern "C" void kernel_launch(void* const* d_in, const int* in_sizes, int n_in,
                              void* d_out, int out_size, void* d_ws, size_t ws_size,
                              hipStream_t stream) {
    const float* x   = (const float*)d_in[0];
    const int*   ei  = (const int*)d_in[1];
    const float* ea  = (const float*)d_in[2];
    const float* Aw  = (const float*)d_in[3];
    const float* Ab  = (const float*)d_in[4];
    const float* Bw  = (const float*)d_in[5];
    const float* Bb  = (const float*)d_in[6];
    const float* q1w = (const float*)d_in[7];  const float* q1b = (const float*)d_in[8];
    const float* k1w = (const float*)d_in[9];  const float* k1b = (const float*)d_in[10];
    const float* v1w = (const float*)d_in[11]; const float* v1b = (const float*)d_in[12];
    const float* e1w = (const float*)d_in[13];
    const float* s1w = (const float*)d_in[14]; const float* s1b = (const float*)d_in[15];
    const float* q2w = (const float*)d_in[16]; const float* q2b = (const float*)d_in[17];
    const float* k2w = (const float*)d_in[18]; const float* k2b = (const float*)d_in[19];
    const float* v2w = (const float*)d_in[20]; const float* v2b = (const float*)d_in[21];
    const float* e2w = (const float*)d_in[22];
    const float* s2w = (const float*)d_in[23]; const float* s2b = (const float*)d_in[24];
    const float* l1w = (const float*)d_in[25]; const float* l1b = (const float*)d_in[26];
    const float* l2w = (const float*)d_in[27]; const float* l2b = (const float*)d_in[28];

    const int n  = in_sizes[0] / 23;
    const int nE = in_sizes[1] / 2;
    const int* src = ei;
    const int* dst = ei + nE;
    float* out = (float*)d_out;
    const int B = 256;
    const int nb = (n + 255) / 256;

    // ---- workspace layout ----
    size_t fl_h1 = (size_t)n * 23;
    size_t fl_o1 = (size_t)n * 192;
    size_t fl_kvA = (size_t)n * 384;   // tierA: k1|v1, later q2|k2|v2|o2 (n*256 used)
    size_t fl_kB  = (size_t)n * 192;   // tierB: k1, later k2|v2|o2
    size_t ints_total = ((size_t)n + 1) + n + n + 1024 + (size_t)nE + (size_t)nE;

    size_t tierA_bytes = (fl_h1 + fl_o1 + fl_kvA) * 4 + ints_total * 4;
    size_t tierB_bytes = (fl_h1 + fl_o1 + fl_kB) * 4 + ints_total * 4;

    if (ws_size < tierB_bytes || nb > 1024) {
        zero_out_kernel<<<(out_size + B - 1) / B, B, 0, stream>>>(out, out_size);
        return;
    }
    const bool tierA = (ws_size >= tierA_bytes);

    float* ws = (float*)d_ws;
    size_t off = 0;
    float* h1   = ws + off; off += fl_h1;
    float* o1   = ws + off; off += fl_o1;
    float* kbuf = ws + off; off += (tierA ? fl_kvA : fl_kB);
    float* vbuf = tierA ? (kbuf + (size_t)n * 192) : nullptr;
    int* ip = (int*)(ws + off);
    int* rp   = ip; ip += (size_t)n + 1;
    int* cnt  = ip; ip += n;
    int* cur  = ip; ip += n;
    int* bsum = ip; ip += 1024;
    int* srcS = ip; ip += nE;
    int* eidS = ip; ip += nE;

    // conv2 buffers alias kbuf region (conv1 edge phase completes first)
    float* q2buf = kbuf;                       // tierA only
    float* k2    = tierA ? (kbuf + (size_t)n * 64)  : kbuf;
    float* v2    = tierA ? (kbuf + (size_t)n * 128) : (kbuf + (size_t)n * 64);
    float* o2    = tierA ? (kbuf + (size_t)n * 192) : (kbuf + (size_t)n * 128);

    const float sc1 = 1.0f / sqrtf(24.0f);
    const float sc2 = 1.0f / sqrtf(8.0f);
    const float* np = nullptr;
    float* npw = nullptr;

    // ---- CSR build ----
    zero2_kernel<<<(n + B - 1) / B, B, 0, stream>>>(cnt, cur, n);
    count_kernel<<<(nE + B - 1) / B, B, 0, stream>>>(dst, cnt, nE);
    scan_block_kernel<<<nb, 256, 0, stream>>>(cnt, bsum, n);
    scan_bsum_kernel<<<1, 1024, 0, stream>>>(bsum, nb);
    finalize_rp_kernel<<<(n + 1 + B - 1) / B, B, 0, stream>>>(cnt, bsum, rp, n, nE);
    scatter_kernel<<<(nE + B - 1) / B, B, 0, stream>>>(src, dst, rp, cur, srcS, eidS, nE);

    // ---- node MLP ----
    mlp_kernel<<<(n + B - 1) / B, B, 0, stream>>>(x, Aw, Ab, Bw, Bb, h1, n);

    // ---- conv1 projections + fused edge phase ----
    if (tierA) {
        proj_multi_kernel<23, 192, 3, 4><<<(n + 3) / 4, dim3(192, 4), 0, stream>>>(
            h1, k1w, k1b, kbuf, v1w, v1b, vbuf, s1w, s1b, o1, np, np, npw, n);
        conv_fused_kernel<23, 24, true, false, true><<<(n + 3) / 4, 256, 0, stream>>>(
            h1, q1w, q1b, v1w, v1b, kbuf, vbuf, np, ea, e1w, rp, srcS, eidS, o1, n, sc1);
    } else {
        proj_multi_kernel<23, 192, 2, 4><<<(n + 3) / 4, dim3(192, 4), 0, stream>>>(
            h1, k1w, k1b, kbuf, s1w, s1b, o1, np, np, npw, np, np, npw, n);
        conv_fused_kernel<23, 24, false, false, true><<<(n + 3) / 4, 256, 0, stream>>>(
            h1, q1w, q1b, v1w, v1b, kbuf, np, np, ea, e1w, rp, srcS, eidS, o1, n, sc1);
    }

    // ---- conv2 projections + fused edge phase ----
    if (tierA) {
        proj_multi_kernel<192, 64, 4, 16><<<(n + 15) / 16, dim3(64, 16), 0, stream>>>(
            o1, q2w, q2b, q2buf, k2w, k2b, k2, v2w, v2b, v2, s2w, s2b, o2, n);
        conv_fused_kernel<192, 8, true, true, false><<<(n + 3) / 4, 256, 0, stream>>>(
            o1, q2w, q2b, v2w, v2b, k2, v2, q2buf, ea, e2w, rp, srcS, eidS, o2, n, sc2);
    } else {
        proj_multi_kernel<192, 64, 3, 16><<<(n + 15) / 16, dim3(64, 16), 0, stream>>>(
            o1, k2w, k2b, k2, v2w, v2b, v2, s2w, s2b, o2, np, np, npw, n);
        conv_fused_kernel<192, 8, true, false, false><<<(n + 3) / 4, 256, 0, stream>>>(
            o1, q2w, q2b, v2w, v2b, k2, v2, np, ea, e2w, rp, srcS, eidS, o2, n, sc2);
    }

    // ---- head ----
    head_kernel<<<(n + B - 1) / B, B, 0, stream>>>(o2, l1w, l1b, l2w, l2b, out, n);
}

// Round 5
// 1103.620 us; speedup vs baseline: 4.5560x; 1.3763x over previous
//
#include <hip/hip_runtime.h>
#include <math.h>

// ---------------- device helpers ----------------

__device__ __forceinline__ float elu_f(float x) {
    return x > 0.f ? x : expm1f(x);
}

// ---------------- node MLP ----------------

__global__ void mlp_kernel(const float* __restrict__ x,
                           const float* __restrict__ A, const float* __restrict__ ab,
                           const float* __restrict__ B, const float* __restrict__ bb,
                           float* __restrict__ out, int n) {
    __shared__ float sA[23 * 23], sB[23 * 23], sa[23], sb[23];
    for (int t = threadIdx.x; t < 23 * 23; t += blockDim.x) { sA[t] = A[t]; sB[t] = B[t]; }
    if (threadIdx.x < 23) { sa[threadIdx.x] = ab[threadIdx.x]; sb[threadIdx.x] = bb[threadIdx.x]; }
    __syncthreads();
    int i = blockIdx.x * blockDim.x + threadIdx.x;
    if (i >= n) return;
    float xi[23], h1[23];
    #pragma unroll
    for (int j = 0; j < 23; j++) xi[j] = x[(size_t)i * 23 + j];
    #pragma unroll
    for (int o = 0; o < 23; o++) {
        float acc = sa[o];
        #pragma unroll
        for (int j = 0; j < 23; j++) acc = fmaf(xi[j], sA[j * 23 + o], acc);
        h1[o] = elu_f(acc);
    }
    #pragma unroll
    for (int o = 0; o < 23; o++) {
        float acc = sb[o];
        #pragma unroll
        for (int j = 0; j < 23; j++) acc = fmaf(h1[j], sB[j * 23 + o], acc);
        out[(size_t)i * 23 + o] = elu_f(acc);
    }
}

// ---------------- register-tiled multi-output projection (GEMM) ----------------
// Computes M projections (width OUTW each) of the same [n x IN] input.
// Tile: BN=32 nodes x WTOT cols. Thread: 4 nodes x 8 cols (two stride-4 float4
// col groups at tx*4 and WTOT/2 + tx*4 -> conflict-free b128 LDS reads).
// Block: CG x TY threads, CG = WTOT/8, nodes per thread-group: TY*4 = BN.
template<int IN, int Kc, int OUTW, int M, int TY>
__global__ void proj_tiled_kernel(const float* __restrict__ in, int n,
    const float* __restrict__ W0, const float* __restrict__ b0, float* __restrict__ o0,
    const float* __restrict__ W1, const float* __restrict__ b1, float* __restrict__ o1,
    const float* __restrict__ W2, const float* __restrict__ b2, float* __restrict__ o2,
    const float* __restrict__ W3, const float* __restrict__ b3, float* __restrict__ o3) {
    constexpr int WTOT = M * OUTW;
    constexpr int CG   = WTOT / 8;
    constexpr int BN   = TY * 4;
    constexpr int SAW  = BN + 4;
    constexpr int NT   = CG * TY;
    static_assert(IN % Kc == 0, "Kc must divide IN");
    static_assert(WTOT % 8 == 0 && OUTW % 4 == 0, "col alignment");
    __shared__ float sA[Kc][SAW];
    __shared__ float sB[Kc][WTOT];

    const int tid = threadIdx.x;
    const int tx = tid % CG;
    const int ty = tid / CG;
    const int node0 = blockIdx.x * BN;

    const int colA = tx * 4;
    const int colB = WTOT / 2 + tx * 4;
    const int matA = colA / OUTW, ccA = colA % OUTW;
    const int matB = colB / OUTW, ccB = colB % OUTW;
    const float* bA = (matA == 0 ? b0 : matA == 1 ? b1 : matA == 2 ? b2 : b3);
    const float* bB = (matB == 0 ? b0 : matB == 1 ? b1 : matB == 2 ? b2 : b3);
    float*       oA = (matA == 0 ? o0 : matA == 1 ? o1 : matA == 2 ? o2 : o3);
    float*       oB = (matB == 0 ? o0 : matB == 1 ? o1 : matB == 2 ? o2 : o3);

    float acc[4][8];
    #pragma unroll
    for (int i = 0; i < 4; i++) {
        #pragma unroll
        for (int c = 0; c < 4; c++) { acc[i][c] = bA[ccA + c]; acc[i][4 + c] = bB[ccB + c]; }
    }

    for (int k0 = 0; k0 < IN; k0 += Kc) {
        // stage A transposed: sA[j][nn] = in[node0+nn][k0+j]
        for (int t = tid; t < Kc * BN; t += NT) {
            int j = t / BN, nn = t - j * BN;
            int g = node0 + nn;
            sA[j][nn] = (g < n) ? in[(size_t)g * IN + k0 + j] : 0.f;
        }
        // stage B: sB[j][c] = W_{c/OUTW}[k0+j][c%OUTW]
        for (int t = tid; t < Kc * WTOT; t += NT) {
            int j = t / WTOT, c = t - j * WTOT;
            int m = c / OUTW, cm = c - m * OUTW;
            const float* Wp = (m == 0 ? W0 : m == 1 ? W1 : m == 2 ? W2 : W3);
            sB[j][c] = Wp[(size_t)(k0 + j) * OUTW + cm];
        }
        __syncthreads();
        #pragma unroll 8
        for (int j = 0; j < Kc; j++) {
            float4 a  = *(const float4*)&sA[j][ty * 4];
            float4 v0 = *(const float4*)&sB[j][colA];
            float4 v1 = *(const float4*)&sB[j][colB];
            float av[4] = {a.x, a.y, a.z, a.w};
            float bv[8] = {v0.x, v0.y, v0.z, v0.w, v1.x, v1.y, v1.z, v1.w};
            #pragma unroll
            for (int i = 0; i < 4; i++)
                #pragma unroll
                for (int c = 0; c < 8; c++)
                    acc[i][c] = fmaf(av[i], bv[c], acc[i][c]);
        }
        __syncthreads();
    }

    #pragma unroll
    for (int i = 0; i < 4; i++) {
        int g = node0 + ty * 4 + i;
        if (g >= n) continue;
        *(float4*)(oA + (size_t)g * OUTW + ccA) = make_float4(acc[i][0], acc[i][1], acc[i][2], acc[i][3]);
        *(float4*)(oB + (size_t)g * OUTW + ccB) = make_float4(acc[i][4], acc[i][5], acc[i][6], acc[i][7]);
    }
}

// ---------------- CSR build ----------------

__global__ void zero2_kernel(int* __restrict__ a, int* __restrict__ b, int n) {
    int i = blockIdx.x * blockDim.x + threadIdx.x;
    if (i < n) { a[i] = 0; b[i] = 0; }
}

__global__ void count_kernel(const int* __restrict__ dst, int* __restrict__ cnt, int nE) {
    int e = blockIdx.x * blockDim.x + threadIdx.x;
    if (e < nE) atomicAdd(&cnt[dst[e]], 1);
}

__global__ void scan_block_kernel(int* __restrict__ cnt, int* __restrict__ bsum, int n) {
    __shared__ int sdat[256];
    int i = blockIdx.x * 256 + threadIdx.x;
    int v = (i < n) ? cnt[i] : 0;
    sdat[threadIdx.x] = v;
    __syncthreads();
    for (int off = 1; off < 256; off <<= 1) {
        int t = (threadIdx.x >= (unsigned)off) ? sdat[threadIdx.x - off] : 0;
        __syncthreads();
        sdat[threadIdx.x] += t;
        __syncthreads();
    }
    if (i < n) cnt[i] = sdat[threadIdx.x] - v;
    if (threadIdx.x == 255) bsum[blockIdx.x] = sdat[255];
}

__global__ void scan_bsum_kernel(int* __restrict__ bsum, int nb) {
    __shared__ int s[1024];
    int i = threadIdx.x;
    int v = (i < nb) ? bsum[i] : 0;
    s[i] = v;
    __syncthreads();
    for (int off = 1; off < 1024; off <<= 1) {
        int t = (i >= off) ? s[i - off] : 0;
        __syncthreads();
        s[i] += t;
        __syncthreads();
    }
    if (i < nb) bsum[i] = s[i] - v;
}

__global__ void finalize_rp_kernel(const int* __restrict__ cnt, const int* __restrict__ bsum,
                                   int* __restrict__ rp, int n, int nE) {
    int i = blockIdx.x * blockDim.x + threadIdx.x;
    if (i < n) rp[i] = cnt[i] + bsum[i >> 8];
    if (i == n) rp[n] = nE;
}

__global__ void scatter_kernel(const int* __restrict__ src, const int* __restrict__ dst,
                               const int* __restrict__ rp, int* __restrict__ cur,
                               int* __restrict__ srcS, int* __restrict__ eidS, int nE) {
    int e = blockIdx.x * blockDim.x + threadIdx.x;
    if (e >= nE) return;
    int d = dst[e];
    int pos = rp[d] + atomicAdd(&cur[d], 1);
    srcS[pos] = src[e];
    eidS[pos] = e;
}

// ---------------- fused TransformerConv (one wave per dst node) ----------------
template<int IN, int C, bool VMAT, bool QMAT, bool DOELU>
__global__ void conv_fused_kernel(const float* __restrict__ feat,
                                  const float* __restrict__ Wq, const float* __restrict__ qb,
                                  const float* __restrict__ Wv, const float* __restrict__ vb,
                                  const float* __restrict__ kmat, const float* __restrict__ vmat,
                                  const float* __restrict__ qmat,
                                  const float* __restrict__ ea, const float* __restrict__ We,
                                  const int* __restrict__ rp, const int* __restrict__ srcS,
                                  const int* __restrict__ eidS,
                                  float* __restrict__ out, int n, float scale) {
    constexpr int HC = 8 * C;
    constexpr int CPL = HC / 64;
    __shared__ float sWv[VMAT ? 1 : IN * HC];
    if constexpr (!VMAT) {
        for (int t = threadIdx.x; t < IN * HC; t += blockDim.x) sWv[t] = Wv[t];
        __syncthreads();
    }
    const int lane = threadIdx.x & 63;
    const int d = blockIdx.x * (blockDim.x >> 6) + (threadIdx.x >> 6);
    if (d >= n) return;
    const int ch0 = lane * CPL;

    float we[7][CPL];
    #pragma unroll
    for (int j = 0; j < 7; j++)
        #pragma unroll
        for (int c = 0; c < CPL; c++) we[j][c] = We[j * HC + ch0 + c];

    float vbr[CPL];
    if constexpr (!VMAT) {
        #pragma unroll
        for (int c = 0; c < CPL; c++) vbr[c] = vb[ch0 + c];
    }

    float* op = out + (size_t)d * HC + ch0;
    float sk[CPL], q[CPL];
    #pragma unroll
    for (int c = 0; c < CPL; c++) sk[c] = op[c];   // pre-stored skip projection
    if constexpr (QMAT) {
        const float* qp = qmat + (size_t)d * HC + ch0;
        #pragma unroll
        for (int c = 0; c < CPL; c++) q[c] = qp[c];
    } else {
        #pragma unroll
        for (int c = 0; c < CPL; c++) q[c] = qb[ch0 + c];
        const float* fd = feat + (size_t)d * IN;
        for (int j = 0; j < IN; j++) {
            float f = fd[j];
            #pragma unroll
            for (int c = 0; c < CPL; c++)
                q[c] = fmaf(f, Wq[(size_t)j * HC + ch0 + c], q[c]);
        }
    }

    float m = -INFINITY, l = 0.f, acc[CPL];
    #pragma unroll
    for (int c = 0; c < CPL; c++) acc[c] = 0.f;

    const int p0 = rp[d], p1 = rp[d + 1];
    for (int p = p0; p < p1; p++) {
        int s = srcS[p];
        int eid = eidS[p];
        const float* eav = ea + (size_t)eid * 7;
        float ev[7];
        #pragma unroll
        for (int j = 0; j < 7; j++) ev[j] = eav[j];

        const float* kp = kmat + (size_t)s * HC + ch0;
        float vv[CPL];
        float part = 0.f;
        #pragma unroll
        for (int c = 0; c < CPL; c++) {
            float ec = 0.f;
            #pragma unroll
            for (int j = 0; j < 7; j++) ec = fmaf(ev[j], we[j][c], ec);
            part = fmaf(q[c], kp[c] + ec, part);
            vv[c] = ec;
        }
        if constexpr (VMAT) {
            const float* vp = vmat + (size_t)s * HC + ch0;
            #pragma unroll
            for (int c = 0; c < CPL; c++) vv[c] += vp[c];
        } else {
            #pragma unroll
            for (int c = 0; c < CPL; c++) vv[c] += vbr[c];
            const float* fs = feat + (size_t)s * IN;
            for (int j = 0; j < IN; j++) {
                float f = fs[j];
                #pragma unroll
                for (int c = 0; c < CPL; c++) vv[c] = fmaf(f, sWv[j * HC + ch0 + c], vv[c]);
            }
        }
        part += __shfl_xor(part, 1);
        part += __shfl_xor(part, 2);
        part += __shfl_xor(part, 4);
        float z = part * scale;
        float mn = fmaxf(m, z);
        float rs = expf(m - mn);
        float pw = expf(z - mn);
        l = l * rs + pw;
        #pragma unroll
        for (int c = 0; c < CPL; c++) acc[c] = fmaf(acc[c], rs, pw * vv[c]);
        m = mn;
    }
    float invl = (l > 0.f) ? 1.f / l : 0.f;
    #pragma unroll
    for (int c = 0; c < CPL; c++) {
        float r = sk[c] + acc[c] * invl;
        op[c] = DOELU ? elu_f(r) : r;
    }
}

// ---------------- head ----------------
__global__ void head_kernel(const float* __restrict__ h, const float* __restrict__ W1,
                            const float* __restrict__ b1, const float* __restrict__ W2,
                            const float* __restrict__ b2, float* __restrict__ out, int n) {
    __shared__ float sW1[64 * 20], sb1[20], sW2[20], sb2;
    for (int t = threadIdx.x; t < 64 * 20; t += blockDim.x) sW1[t] = W1[t];
    if (threadIdx.x < 20) { sb1[threadIdx.x] = b1[threadIdx.x]; sW2[threadIdx.x] = W2[threadIdx.x]; }
    if (threadIdx.x == 0) sb2 = b2[0];
    __syncthreads();
    int i = blockIdx.x * blockDim.x + threadIdx.x;
    if (i >= n) return;
    float hv[64];
    const float* hp = h + (size_t)i * 64;
    #pragma unroll
    for (int j = 0; j < 64; j++) hv[j] = elu_f(hp[j]);
    float acc2 = sb2;
    for (int o = 0; o < 20; o++) {
        float a = sb1[o];
        #pragma unroll
        for (int j = 0; j < 64; j++) a = fmaf(hv[j], sW1[j * 20 + o], a);
        acc2 = fmaf(elu_f(a), sW2[o], acc2);
    }
    out[i] = acc2;
}

__global__ void zero_out_kernel(float* __restrict__ out, int n) {
    int i = blockIdx.x * blockDim.x + threadIdx.x;
    if (i < n) out[i] = 0.f;
}

// ---------------- launcher ----------------

extern "C" void kernel_launch(void* const* d_in, const int* in_sizes, int n_in,
                              void* d_out, int out_size, void* d_ws, size_t ws_size,
                              hipStream_t stream) {
    const float* x   = (const float*)d_in[0];
    const int*   ei  = (const int*)d_in[1];
    const float* ea  = (const float*)d_in[2];
    const float* Aw  = (const float*)d_in[3];
    const float* Ab  = (const float*)d_in[4];
    const float* Bw  = (const float*)d_in[5];
    const float* Bb  = (const float*)d_in[6];
    const float* q1w = (const float*)d_in[7];  const float* q1b = (const float*)d_in[8];
    const float* k1w = (const float*)d_in[9];  const float* k1b = (const float*)d_in[10];
    const float* v1w = (const float*)d_in[11]; const float* v1b = (const float*)d_in[12];
    const float* e1w = (const float*)d_in[13];
    const float* s1w = (const float*)d_in[14]; const float* s1b = (const float*)d_in[15];
    const float* q2w = (const float*)d_in[16]; const float* q2b = (const float*)d_in[17];
    const float* k2w = (const float*)d_in[18]; const float* k2b = (const float*)d_in[19];
    const float* v2w = (const float*)d_in[20]; const float* v2b = (const float*)d_in[21];
    const float* e2w = (const float*)d_in[22];
    const float* s2w = (const float*)d_in[23]; const float* s2b = (const float*)d_in[24];
    const float* l1w = (const float*)d_in[25]; const float* l1b = (const float*)d_in[26];
    const float* l2w = (const float*)d_in[27]; const float* l2b = (const float*)d_in[28];

    const int n  = in_sizes[0] / 23;
    const int nE = in_sizes[1] / 2;
    const int* src = ei;
    const int* dst = ei + nE;
    float* out = (float*)d_out;
    const int B = 256;
    const int nb = (n + 255) / 256;

    // ---- workspace layout ----
    size_t fl_h1 = ((size_t)n * 23 + 3) & ~(size_t)3;
    size_t fl_o1 = (size_t)n * 192;
    size_t fl_kvA = (size_t)n * 384;   // tierA: k1|v1, later q2|k2|v2|o2
    size_t fl_kB  = (size_t)n * 192;   // tierB: k1, later k2|v2|o2
    size_t ints_total = ((size_t)n + 1) + n + n + 1024 + (size_t)nE + (size_t)nE;

    size_t tierA_bytes = (fl_h1 + fl_o1 + fl_kvA) * 4 + ints_total * 4;
    size_t tierB_bytes = (fl_h1 + fl_o1 + fl_kB) * 4 + ints_total * 4;

    if (ws_size < tierB_bytes || nb > 1024) {
        zero_out_kernel<<<(out_size + B - 1) / B, B, 0, stream>>>(out, out_size);
        return;
    }
    const bool tierA = (ws_size >= tierA_bytes);

    float* ws = (float*)d_ws;
    size_t off = 0;
    float* h1   = ws + off; off += fl_h1;
    float* o1   = ws + off; off += fl_o1;
    float* kbuf = ws + off; off += (tierA ? fl_kvA : fl_kB);
    float* vbuf = tierA ? (kbuf + (size_t)n * 192) : nullptr;
    int* ip = (int*)(ws + off);
    int* rp   = ip; ip += (size_t)n + 1;
    int* cnt  = ip; ip += n;
    int* cur  = ip; ip += n;
    int* bsum = ip; ip += 1024;
    int* srcS = ip; ip += nE;
    int* eidS = ip; ip += nE;

    // conv2 buffers alias kbuf region (conv1 edge phase completes first)
    float* q2buf = kbuf;                       // tierA only
    float* k2    = tierA ? (kbuf + (size_t)n * 64)  : kbuf;
    float* v2    = tierA ? (kbuf + (size_t)n * 128) : (kbuf + (size_t)n * 64);
    float* o2    = tierA ? (kbuf + (size_t)n * 192) : (kbuf + (size_t)n * 128);

    const float sc1 = 1.0f / sqrtf(24.0f);
    const float sc2 = 1.0f / sqrtf(8.0f);
    const float* np = nullptr;
    float* npw = nullptr;

    // ---- CSR build ----
    zero2_kernel<<<(n + B - 1) / B, B, 0, stream>>>(cnt, cur, n);
    count_kernel<<<(nE + B - 1) / B, B, 0, stream>>>(dst, cnt, nE);
    scan_block_kernel<<<nb, 256, 0, stream>>>(cnt, bsum, n);
    scan_bsum_kernel<<<1, 1024, 0, stream>>>(bsum, nb);
    finalize_rp_kernel<<<(n + 1 + B - 1) / B, B, 0, stream>>>(cnt, bsum, rp, n, nE);
    scatter_kernel<<<(nE + B - 1) / B, B, 0, stream>>>(src, dst, rp, cur, srcS, eidS, nE);

    // ---- node MLP ----
    mlp_kernel<<<(n + B - 1) / B, B, 0, stream>>>(x, Aw, Ab, Bw, Bb, h1, n);

    const int gproj = (n + 31) / 32;

    // ---- conv1 projections + fused edge phase ----
    if (tierA) {
        // k,v,s : 23 -> 192 x3 (WTOT=576, CG=72, block 576)
        proj_tiled_kernel<23, 23, 192, 3, 8><<<gproj, 576, 0, stream>>>(
            h1, n, k1w, k1b, kbuf, v1w, v1b, vbuf, s1w, s1b, o1, np, np, npw);
        conv_fused_kernel<23, 24, true, false, true><<<(n + 3) / 4, 256, 0, stream>>>(
            h1, q1w, q1b, v1w, v1b, kbuf, vbuf, np, ea, e1w, rp, srcS, eidS, o1, n, sc1);
    } else {
        // k,s : 23 -> 192 x2 (WTOT=384, CG=48, block 384)
        proj_tiled_kernel<23, 23, 192, 2, 8><<<gproj, 384, 0, stream>>>(
            h1, n, k1w, k1b, kbuf, s1w, s1b, o1, np, np, npw, np, np, npw);
        conv_fused_kernel<23, 24, false, false, true><<<(n + 3) / 4, 256, 0, stream>>>(
            h1, q1w, q1b, v1w, v1b, kbuf, np, np, ea, e1w, rp, srcS, eidS, o1, n, sc1);
    }

    // ---- conv2 projections + fused edge phase ----
    if (tierA) {
        // q,k,v,s : 192 -> 64 x4 (WTOT=256, CG=32, block 256)
        proj_tiled_kernel<192, 32, 64, 4, 8><<<gproj, 256, 0, stream>>>(
            o1, n, q2w, q2b, q2buf, k2w, k2b, k2, v2w, v2b, v2, s2w, s2b, o2);
        conv_fused_kernel<192, 8, true, true, false><<<(n + 3) / 4, 256, 0, stream>>>(
            o1, q2w, q2b, v2w, v2b, k2, v2, q2buf, ea, e2w, rp, srcS, eidS, o2, n, sc2);
    } else {
        // k,v,s : 192 -> 64 x3 (WTOT=192, CG=24, block 192)
        proj_tiled_kernel<192, 32, 64, 3, 8><<<gproj, 192, 0, stream>>>(
            o1, n, k2w, k2b, k2, v2w, v2b, v2, s2w, s2b, o2, np, np, npw);
        conv_fused_kernel<192, 8, true, false, false><<<(n + 3) / 4, 256, 0, stream>>>(
            o1, q2w, q2b, v2w, v2b, k2, v2, np, ea, e2w, rp, srcS, eidS, o2, n, sc2);
    }

    // ---- head ----
    head_kernel<<<(n + B - 1) / B, B, 0, stream>>>(o2, l1w, l1b, l2w, l2b, out, n);
}